// Round 1
// baseline (1003.150 us; speedup 1.0000x reference)
//
#include <hip/hip_runtime.h>

// ---------------------------------------------------------------------------
// ActivatedHeteroLinear: out = LeakyReLU(BN_train(x @ (W1@W2)))
// Biases b1,b2 are annihilated by BatchNorm's mean subtraction.
// Two passes per type (BN needs full-batch stats): pass1 = GEMM + stats,
// pass2 = recompute GEMM + normalize + LeakyReLU.  bf16 MFMA, fp32 accum.
// ---------------------------------------------------------------------------

typedef __attribute__((ext_vector_type(8))) short bf16x8;   // 8 bf16 in 4 VGPRs
typedef __attribute__((ext_vector_type(4))) float f32x4;

#define NBUF 128   // replicated atomic stat buffers (contention spreading)

// workspace layout (float offsets)
#define WT_U_OFF    0                       // 128x64 bf16  = 4096 floats
#define WT_I_OFF    4096                    // 128x128 bf16 = 8192 floats
#define SUM_U_OFF   12288                   // NBUF*128 each
#define SQ_U_OFF    (12288 + 1*NBUF*128)
#define SUM_I_OFF   (12288 + 2*NBUF*128)
#define SQ_I_OFF    (12288 + 3*NBUF*128)
#define SCALE_U_OFF (12288 + 4*NBUF*128)
#define SHIFT_U_OFF (SCALE_U_OFF + 128)
#define SCALE_I_OFF (SCALE_U_OFF + 256)
#define SHIFT_I_OFF (SCALE_U_OFF + 384)

__device__ inline unsigned short f2bf(float f) {
  union { float f; unsigned u; } v; v.f = f;
  return (unsigned short)((v.u + 0x7fffu + ((v.u >> 16) & 1u)) >> 16);  // RNE
}

// K0: zero stat buffers + compute fused weights Wt[c][k] = sum_j W1[k][j]*W2[j][c]
__global__ void fuse_zero_kernel(const float* __restrict__ W1u, const float* __restrict__ W2u,
                                 const float* __restrict__ W1i, const float* __restrict__ W2i,
                                 float* __restrict__ ws) {
  const int b = blockIdx.x;   // 192 blocks: 0..63 user-k, 64..191 item-k
  const int c = threadIdx.x;  // 128 threads = output channel
  const int tid = b * 128 + c;
  for (int i = tid; i < 4 * NBUF * 128; i += 192 * 128) ws[SUM_U_OFF + i] = 0.f;

  const float* W1; const float* W2; int k; unsigned short* wt; int K;
  if (b < 64) { W1 = W1u; W2 = W2u; k = b;      wt = (unsigned short*)(ws + WT_U_OFF); K = 64; }
  else        { W1 = W1i; W2 = W2i; k = b - 64; wt = (unsigned short*)(ws + WT_I_OFF); K = 128; }
  float s = 0.f;
  for (int j = 0; j < 256; ++j) s += W1[k * 256 + j] * W2[j * 128 + c];
  wt[c * K + k] = f2bf(s);   // transposed [128][K] for contiguous B-fragment reads
}

// K3: reduce replicated stats -> scale/shift per channel per type
__global__ void finalize_kernel(float* __restrict__ ws,
                                const float* __restrict__ gU, const float* __restrict__ bU,
                                const float* __restrict__ gI, const float* __restrict__ bI,
                                float invNu, float invNi) {
  const int typ = blockIdx.x;   // 0=user 1=item
  const int c = threadIdx.x;    // 128
  const float* sums = ws + (typ ? SUM_I_OFF : SUM_U_OFF);
  const float* sqs  = ws + (typ ? SQ_I_OFF  : SQ_U_OFF);
  const float invN  = typ ? invNi : invNu;
  float s = 0.f, q = 0.f;
  for (int b2 = 0; b2 < NBUF; ++b2) { s += sums[b2 * 128 + c]; q += sqs[b2 * 128 + c]; }
  const float mean = s * invN;
  const float var  = q * invN - mean * mean;   // biased variance (matches ref)
  const float* g  = typ ? gI : gU;
  const float* be = typ ? bI : bU;
  const float sc = g[c] * rsqrtf(var + 1e-5f);
  const float sh = be[c] - mean * sc;
  ws[(typ ? SCALE_I_OFF : SCALE_U_OFF) + c] = sc;
  ws[(typ ? SHIFT_I_OFF : SHIFT_U_OFF) + c] = sh;
}

// Main GEMM: block = 256 thr (4 waves), tile = 64 rows x 128 cols, K = 64|128.
// Each wave: 16 rows x 8 col-tiles of mfma_f32_16x16x32_bf16.
// LDS padded +8 bf16 per row -> 2-way bank aliasing only (free on CDNA4).
template <int K, bool STATS>
__global__ __launch_bounds__(256) void hgemm_kernel(
    const float* __restrict__ x,                 // [N, K] fp32
    const unsigned short* __restrict__ wt,       // [128][K] bf16 bits
    float* __restrict__ sum_buf, float* __restrict__ sq_buf,     // STATS
    const float* __restrict__ scale, const float* __restrict__ shift,
    float* __restrict__ out)                     // [N, 128] fp32
{
  constexpr int KP = K + 8;
  __shared__ __align__(16) unsigned short xs[64 * KP];
  __shared__ __align__(16) unsigned short wsh[128 * KP];
  __shared__ float bsum[128];
  __shared__ float bsq[128];

  const int tid = threadIdx.x;
  const long long row0 = (long long)blockIdx.x * 64;

  if (STATS && tid < 128) { bsum[tid] = 0.f; bsq[tid] = 0.f; }

  // stage W tile (bf16, already transposed): 8 bf16 per uint4
  {
    const uint4* src = (const uint4*)wt;
    constexpr int CH = 128 * K / 8;
    for (int i = tid; i < CH; i += 256) {
      const int r = (i * 8) / K, cc = (i * 8) % K;
      *(uint4*)&wsh[r * KP + cc] = src[i];
    }
  }
  // stage X tile: contiguous fp32 rows -> bf16 LDS
  {
    const float4* src = (const float4*)(x + row0 * K);
    constexpr int CH = 64 * K / 4;
    for (int i = tid; i < CH; i += 256) {
      const float4 v = src[i];
      const int r = (i * 4) / K, cc = (i * 4) % K;
      ushort4 p;
      p.x = f2bf(v.x); p.y = f2bf(v.y); p.z = f2bf(v.z); p.w = f2bf(v.w);
      *(ushort4*)&xs[r * KP + cc] = p;
    }
  }
  __syncthreads();

  const int lane = tid & 63;
  const int wave = tid >> 6;
  const int l16  = lane & 15;
  const int quad = lane >> 4;
  const int arow = wave * 16 + l16;

  f32x4 acc[8];
#pragma unroll
  for (int t = 0; t < 8; ++t) acc[t] = (f32x4){0.f, 0.f, 0.f, 0.f};

#pragma unroll
  for (int k0 = 0; k0 < K; k0 += 32) {
    // A fragment: A[m=lane&15][k = quad*8 + j]
    const bf16x8 a = *(const bf16x8*)&xs[arow * KP + k0 + quad * 8];
#pragma unroll
    for (int t = 0; t < 8; ++t) {
      // B fragment: B[k = quad*8 + j][n = lane&15]  == Wt[n][k] (transposed store)
      const bf16x8 b = *(const bf16x8*)&wsh[(t * 16 + l16) * KP + k0 + quad * 8];
      acc[t] = __builtin_amdgcn_mfma_f32_16x16x32_bf16(a, b, acc[t], 0, 0, 0);
    }
  }

  if (STATS) {
    // C layout: col = lane&15, row = quad*4 + reg. Lane partials over its 4 rows,
    // then reduce across quads (lanes sharing a column) via xor-shuffles.
#pragma unroll
    for (int t = 0; t < 8; ++t) {
      float s1 = acc[t][0] + acc[t][1] + acc[t][2] + acc[t][3];
      float s2 = acc[t][0] * acc[t][0] + acc[t][1] * acc[t][1] +
                 acc[t][2] * acc[t][2] + acc[t][3] * acc[t][3];
      s1 += __shfl_xor(s1, 16, 64);  s2 += __shfl_xor(s2, 16, 64);
      s1 += __shfl_xor(s1, 32, 64);  s2 += __shfl_xor(s2, 32, 64);
      if (quad == 0) {
        atomicAdd(&bsum[t * 16 + l16], s1);
        atomicAdd(&bsq[t * 16 + l16], s2);
      }
    }
    __syncthreads();
    if (tid < 128) {
      const int buf = blockIdx.x & (NBUF - 1);
      atomicAdd(&sum_buf[buf * 128 + tid], bsum[tid]);
      atomicAdd(&sq_buf[buf * 128 + tid], bsq[tid]);
    }
  } else {
#pragma unroll
    for (int t = 0; t < 8; ++t) {
      const int c = t * 16 + l16;
      const float sc = scale[c];
      const float sh = shift[c];
#pragma unroll
      for (int i = 0; i < 4; ++i) {
        const long long r = row0 + wave * 16 + quad * 4 + i;
        float v = acc[t][i] * sc + sh;
        v = (v >= 0.f) ? v : 0.01f * v;
        out[r * 128 + c] = v;
      }
    }
  }
}

extern "C" void kernel_launch(void* const* d_in, const int* in_sizes, int n_in,
                              void* d_out, int out_size, void* d_ws, size_t ws_size,
                              hipStream_t stream) {
  const float* xu  = (const float*)d_in[0];
  const float* xi  = (const float*)d_in[1];
  const float* W1u = (const float*)d_in[2];
  const float* W1i = (const float*)d_in[4];
  const float* W2u = (const float*)d_in[6];
  const float* W2i = (const float*)d_in[8];
  const float* gU  = (const float*)d_in[10];
  const float* bU  = (const float*)d_in[11];
  const float* gI  = (const float*)d_in[12];
  const float* bI  = (const float*)d_in[13];
  float* ws = (float*)d_ws;

  const int Nu = in_sizes[0] / 64;    // 400000
  const int Ni = in_sizes[1] / 128;   // 600000
  float* outU = (float*)d_out;
  float* outI = outU + (long long)Nu * 128;

  hipLaunchKernelGGL(fuse_zero_kernel, dim3(192), dim3(128), 0, stream,
                     W1u, W2u, W1i, W2i, ws);
  hipLaunchKernelGGL((hgemm_kernel<64, true>), dim3(Nu / 64), dim3(256), 0, stream,
                     xu, (const unsigned short*)(ws + WT_U_OFF),
                     ws + SUM_U_OFF, ws + SQ_U_OFF, nullptr, nullptr, nullptr);
  hipLaunchKernelGGL((hgemm_kernel<128, true>), dim3(Ni / 64), dim3(256), 0, stream,
                     xi, (const unsigned short*)(ws + WT_I_OFF),
                     ws + SUM_I_OFF, ws + SQ_I_OFF, nullptr, nullptr, nullptr);
  hipLaunchKernelGGL(finalize_kernel, dim3(2), dim3(128), 0, stream,
                     ws, gU, bU, gI, bI, 1.f / (float)Nu, 1.f / (float)Ni);
  hipLaunchKernelGGL((hgemm_kernel<64, false>), dim3(Nu / 64), dim3(256), 0, stream,
                     xu, (const unsigned short*)(ws + WT_U_OFF), nullptr, nullptr,
                     ws + SCALE_U_OFF, ws + SHIFT_U_OFF, outU);
  hipLaunchKernelGGL((hgemm_kernel<128, false>), dim3(Ni / 64), dim3(256), 0, stream,
                     xi, (const unsigned short*)(ws + WT_I_OFF), nullptr, nullptr,
                     ws + SCALE_I_OFF, ws + SHIFT_I_OFF, outI);
}